// Round 7
// baseline (806.951 us; speedup 1.0000x reference)
//
#include <hip/hip_runtime.h>
#include <stdint.h>

#define B_ 2
#define T_ 4096
#define D_ 512
#define H_ 8
#define DH_ 64

typedef __bf16 bf16;
typedef __bf16 bf16x4_t __attribute__((ext_vector_type(4)));
typedef __bf16 bf16x8_t __attribute__((ext_vector_type(8)));
typedef float f32x4 __attribute__((ext_vector_type(4)));
typedef short short4_t __attribute__((ext_vector_type(4)));
typedef uint32_t u32;

static constexpr float QSCALE = 0.18033688011112042f;   // log2(e)/8 (folded into Wq,bq)

__device__ __forceinline__ void async16(void* lds, const void* g) {
  __builtin_amdgcn_global_load_lds(
      (const __attribute__((address_space(1))) void*)g,
      (__attribute__((address_space(3))) void*)lds, 16, 0, 0);
}

// ---------------------------------------------------------------- prep ----
__global__ __launch_bounds__(256) void prep_kernel(
    const float* __restrict__ x,
    const float* __restrict__ Wq, const float* __restrict__ Wk,
    const float* __restrict__ Wv, const float* __restrict__ Wo,
    const void* __restrict__ maskp,
    bf16* __restrict__ xb, bf16* __restrict__ WTall, bf16* __restrict__ WoT,
    u32* __restrict__ bmask)
{
  int bid = blockIdx.x;
  int tid = threadIdx.x;
  if (bid < 4096) {
    int idx = bid * 256 + tid;
    const float4* xf = (const float4*)x;
    float4 v = xf[idx];
    bf16x4_t o;
    o[0] = (bf16)v.x; o[1] = (bf16)v.y; o[2] = (bf16)v.z; o[3] = (bf16)v.w;
    ((bf16x4_t*)xb)[idx] = o;
  } else if (bid < 8192) {
    int gid = (bid - 4096) * 256 + tid;
    int sel = gid >> 18;
    int idx = gid & 262143;
    int n = idx >> 9, k = idx & 511;
    if (sel < 3) {
      const float* W = (sel == 0) ? Wq : (sel == 1) ? Wk : Wv;
      float v = W[k * 512 + n];
      if (sel == 0) v *= QSCALE;
      WTall[gid] = (bf16)v;
    } else {
      WoT[idx] = (bf16)Wo[k * 512 + n];
    }
  } else {
    int wid = (bid - 8192) * 256 + tid;   // 524,288 words
    const uint8_t* m8 = (const uint8_t*)maskp;
    bool u8mode = (__ballot(m8[4 * (tid & 63) + 1] != 0) != 0ull);
    int row = wid >> 7, wcol = wid & 127;
    size_t off = (size_t)row * 4096 + (size_t)wcol * 32;
    u32 w = 0;
    if (u8mode) {
      const uint4* p = (const uint4*)(m8 + off);
      uint4 a = p[0], b = p[1];
      u32 ws[8] = {a.x, a.y, a.z, a.w, b.x, b.y, b.z, b.w};
      #pragma unroll
      for (int j = 0; j < 32; ++j)
        if ((ws[j >> 2] >> ((j & 3) * 8)) & 0xffu) w |= (1u << j);
    } else {
      const uint4* p = (const uint4*)((const u32*)maskp + off);
      #pragma unroll
      for (int q = 0; q < 8; ++q) {
        uint4 a = p[q];
        if (a.x) w |= 1u << (q * 4 + 0);
        if (a.y) w |= 1u << (q * 4 + 1);
        if (a.z) w |= 1u << (q * 4 + 2);
        if (a.w) w |= 1u << (q * 4 + 3);
      }
    }
    bmask[((size_t)(row >> 6) * 64 + (wcol >> 1)) * 128 + (row & 63) * 2 + (wcol & 1)] = w;
  }
}

// ---------------------------------------------------------- QKV GEMM -------
// 128x128 tiles: 4 waves, each owns a 64x64 sub-tile. BK=64, 2-barrier.
// LDS-transpose epilogue -> fully coalesced 16B output stores.
__global__ __launch_bounds__(256) void qkv_kernel(
    const bf16* __restrict__ xb, const bf16* __restrict__ WTall,
    const float* __restrict__ bq, const float* __restrict__ bk,
    const float* __restrict__ bv,
    bf16* __restrict__ Qb, bf16* __restrict__ Kb, bf16* __restrict__ Vtb)
{
  __shared__ char smem[32768];
  char* smX = smem;                 // 128 rows x 128B (swizzled)
  char* smW = smem + 16384;         // 128 rows x 128B
  int tid = threadIdx.x;
  int lane = tid & 63, wave = tid >> 6;
  int lo = lane & 15, quad = lane >> 4;
  int wr = wave >> 1, wc = wave & 1;
  int bm = blockIdx.x * 128;
  int bn = blockIdx.y * 128;
  int sel = bn >> 9;   // 0=Q 1=K 2=V
  f32x4 acc[4][4] = {};
  for (int kc = 0; kc < 8; ++kc) {
    __syncthreads();
    #pragma unroll
    for (int i = 0; i < 4; ++i) {
      int s = tid + i * 256;
      int row = s >> 3, slot = s & 7;
      int cg = slot ^ (row & 7) ^ ((row >> 3) & 1);
      async16(smX + s * 16, xb + (size_t)(bm + row) * 512 + kc * 64 + cg * 8);
      async16(smW + s * 16, WTall + (size_t)(bn + row) * 512 + kc * 64 + cg * 8);
    }
    __syncthreads();
    #pragma unroll
    for (int ks = 0; ks < 2; ++ks) {
      bf16x8_t a[4], b[4];
      #pragma unroll
      for (int mt = 0; mt < 4; ++mt) {
        int row = wr * 64 + mt * 16 + lo;
        int ch = (ks * 4 + quad) ^ (row & 7) ^ ((row >> 3) & 1);
        a[mt] = *(const bf16x8_t*)(smX + row * 128 + ch * 16);
      }
      #pragma unroll
      for (int nt = 0; nt < 4; ++nt) {
        int row = wc * 64 + nt * 16 + lo;
        int ch = (ks * 4 + quad) ^ (row & 7) ^ ((row >> 3) & 1);
        b[nt] = *(const bf16x8_t*)(smW + row * 128 + ch * 16);
      }
      if (sel < 2) {
        #pragma unroll
        for (int mt = 0; mt < 4; ++mt)
          #pragma unroll
          for (int nt = 0; nt < 4; ++nt)
            acc[mt][nt] = __builtin_amdgcn_mfma_f32_16x16x32_bf16(
                b[nt], a[mt], acc[mt][nt], 0, 0, 0);   // D: m=W-row, n=t
      } else {
        #pragma unroll
        for (int mt = 0; mt < 4; ++mt)
          #pragma unroll
          for (int nt = 0; nt < 4; ++nt)
            acc[mt][nt] = __builtin_amdgcn_mfma_f32_16x16x32_bf16(
                a[mt], b[nt], acc[mt][nt], 0, 0, 0);   // D: m=t, n=W-row
      }
    }
  }
  int b_ = bm >> 12;
  // ---- epilogue: acc -> swizzled LDS tile -> coalesced 16B copy-out ----
  __syncthreads();                      // all waves done reading smX/smW
  char* smT = smem;                     // 128x128 bf16 = 32768 B, chunk-swizzled
  if (sel < 2) {
    const float* bias = (sel == 0) ? bq : bk;
    bf16* base = (sel == 0) ? Qb : Kb;
    #pragma unroll
    for (int mt = 0; mt < 4; ++mt) {
      int tl = wr * 64 + mt * 16 + lo;
      #pragma unroll
      for (int nt = 0; nt < 4; ++nt) {
        int c0 = wc * 64 + nt * 16 + quad * 4;
        bf16x4_t v;
        #pragma unroll
        for (int r = 0; r < 4; ++r) {
          float bs = bias[(bn & 511) + c0 + r];
          if (sel == 0) bs *= QSCALE;
          v[r] = (bf16)(acc[mt][nt][r] + bs);
        }
        int chunk = (c0 >> 3) ^ (tl & 15);
        int half = (c0 >> 2) & 1;
        *(bf16x4_t*)(smT + tl * 256 + chunk * 16 + half * 8) = v;
      }
    }
    __syncthreads();
    #pragma unroll
    for (int it = 0; it < 8; ++it) {
      int i = tid + it * 256;
      int tl = i >> 4, c = i & 15;
      bf16x8_t v = *(const bf16x8_t*)(smT + tl * 256 + ((c ^ (tl & 15)) * 16));
      int colg = (bn & 511) + c * 8;
      int h = colg >> 6, dh0 = colg & 63;
      int t = (bm & 4095) + tl;
      *(bf16x8_t*)(base + (size_t)(b_ * H_ + h) * T_ * DH_ +
                   (size_t)t * 64 + dh0) = v;
    }
  } else {
    #pragma unroll
    for (int nt = 0; nt < 4; ++nt) {
      int dhl = wc * 64 + nt * 16 + lo;
      float bs = bv[(bn & 511) + dhl];
      #pragma unroll
      for (int mt = 0; mt < 4; ++mt) {
        int t0 = wr * 64 + mt * 16 + quad * 4;
        bf16x4_t v;
        #pragma unroll
        for (int r = 0; r < 4; ++r) v[r] = (bf16)(acc[mt][nt][r] + bs);
        int chunk = (t0 >> 3) ^ (dhl & 15);
        int half = (t0 >> 2) & 1;
        *(bf16x4_t*)(smT + dhl * 256 + chunk * 16 + half * 8) = v;
      }
    }
    __syncthreads();
    #pragma unroll
    for (int it = 0; it < 8; ++it) {
      int i = tid + it * 256;
      int dhl = i >> 4, c = i & 15;
      bf16x8_t v = *(const bf16x8_t*)(smT + dhl * 256 + ((c ^ (dhl & 15)) * 16));
      int colg = (bn & 511) + dhl;
      int h = colg >> 6, dh = colg & 63;
      int t = (bm & 4095) + c * 8;
      *(bf16x8_t*)(Vtb + ((size_t)(b_ * H_ + h) * DH_ + dh) * T_ + t) = v;
    }
  }
}

// ------------------------------------------------------ flash attention ----
// 8-wave (512-thread) blocks at FULL occupancy (32 waves/CU; was 16).
// Waves = (qh in {0,1}) x (khh in {0..3}). Per chunk-iteration the block
// stages 128 keys as TWO independent R4-geometry buffer pairs:
//   K0/V0 = keys [0,64), K1/V1 = keys [64,128), each [64 rows][128B] with
//   the proven SWZ (R4's 393K-conflict pattern, byte-identical reads/writes).
// Wave khh computes its 32-key strip in half=khh>>1 with kh=khh&1 -- the
// per-wave instruction stream is exactly R4's. Barrier pairs 64 -> 32.
// Epilogue: barrier-sequenced 4-way kh combine in LDS.
#define SWZ(r) (((r) & 3) | ((((r) >> 3) & 1) << 2))

__global__ __launch_bounds__(512, 8) void attn_kernel(
    const bf16* __restrict__ Qb, const bf16* __restrict__ Kb,
    const bf16* __restrict__ Vtb, const u32* __restrict__ bm2,
    bf16* __restrict__ Obuf)
{
  __shared__ char smem[34816];
  // [0,8192) K half0 | [8192,16384) V half0 | [16384,24576) K half1 |
  // [24576,32768) V half1 | mask 1KB | rowsum partials 4x64 f32
  u32* smM = (u32*)(smem + 32768);      // 1024B: 256 mask words
  float* smL = (float*)(smem + 33792);  // 4 x 64 f32 rowsum partials
  int tid = threadIdx.x;
  int lane = tid & 63, wave = tid >> 6;   // 0..7
  int lo = lane & 15, quad = lane >> 4;
  int qh = wave & 1;
  int khh = wave >> 1;                  // 0..3 key strip
  int kh = khh & 1, half = khh >> 1;
  const char* bK = smem + half * 16384;
  const char* bV = smem + half * 16384 + 8192;
  int blk = blockIdx.x;
  int bh = blk & 15;                    // XCD-aware: bh pinned per XCD
  int qt64 = blk >> 4;
  int qbase = qt64 * 64;

  const bf16* Kg = Kb + (size_t)bh * T_ * DH_;
  const bf16* Vg = Vtb + (size_t)bh * DH_ * T_;
  const u32* mg = bm2 + (size_t)qt64 * 8192;

  // preload Q fragments (loop-invariant); B operand of mfma(K,Q)
  const bf16* Qg = Qb + ((size_t)bh * T_ + qbase + qh * 32) * DH_;
  bf16x8_t qf[2][2];
  #pragma unroll
  for (int qt = 0; qt < 2; ++qt)
    #pragma unroll
    for (int ks = 0; ks < 2; ++ks)
      qf[qt][ks] = *(const bf16x8_t*)(Qg + (qt * 16 + lo) * 64 + ks * 32 + quad * 8);

  // ones-column B-frag for K=32 rowsum MFMA (col n=0 -> lanes lo==0)
  bf16 onev = (lo == 0) ? (bf16)1.0f : (bf16)0.0f;
  bf16x8_t ones8 = {onev, onev, onev, onev, onev, onev, onev, onev};

  f32x4 O[2][4] = {};
  f32x4 Ol[2] = {};

  for (int kc2 = 0; kc2 < 32; ++kc2) {
    __syncthreads();                    // prior compute done: safe to restage
    {
      int row = tid >> 3, slot = tid & 7;      // tid<512 -> row 0..63
      int cg = slot ^ SWZ(row);
      async16(smem + tid * 16,         Kg + (size_t)(kc2 * 128 + row) * 64 + cg * 8);
      async16(smem + 8192 + tid * 16,  Vg + (size_t)row * T_ + kc2 * 128 + cg * 8);
      async16(smem + 16384 + tid * 16, Kg + (size_t)(kc2 * 128 + 64 + row) * 64 + cg * 8);
      async16(smem + 24576 + tid * 16, Vg + (size_t)row * T_ + kc2 * 128 + 64 + cg * 8);
    }
    if (tid < 64) async16((char*)smM + tid * 16, mg + kc2 * 256 + tid * 4);
    __syncthreads();                    // staging visible

    // S^T = K Q^T; permuted K-row feed (within this wave's 64-key half):
    // krow = kh*32 + (lo>>2)*8 + kt*4 + (lo&3)
    //  -> St[kt][qt][r] holds k(within strip) = quad*8 + kt*4 + r
    f32x4 St[2][2] = {};
    __builtin_amdgcn_s_setprio(1);
    #pragma unroll
    for (int ks = 0; ks < 2; ++ks)
      #pragma unroll
      for (int kt = 0; kt < 2; ++kt) {
        int krow = kh * 32 + ((lo >> 2) << 3) + kt * 4 + (lo & 3);
        int ch = (ks * 4 + quad) ^ SWZ(krow);
        bf16x8_t kf = *(const bf16x8_t*)(bK + krow * 128 + ch * 16);
        #pragma unroll
        for (int qt = 0; qt < 2; ++qt)
          St[kt][qt] = __builtin_amdgcn_mfma_f32_16x16x32_bf16(
              kf, qf[qt][ks], St[kt][qt], 0, 0, 0);
      }
    __builtin_amdgcn_s_setprio(0);
    // mask (sext bitfield + AND) + exp2 + pack to K=32 PV A-frags
    bf16x8_t pf8[2];   // [qt]: elem j=kt*4+r -> k = quad*8 + j (within strip)
    #pragma unroll
    for (int qt = 0; qt < 2; ++qt) {
      u32 w = smM[half * 128 + (qh * 32 + qt * 16 + lo) * 2 + kh];
      bf16x8_t t;
      #pragma unroll
      for (int kt = 0; kt < 2; ++kt)
        #pragma unroll
        for (int r = 0; r < 4; ++r) {
          int bit = quad * 8 + kt * 4 + r;
          int mb = ((int)(w << (31 - bit))) >> 31;
          u32 pe = __builtin_bit_cast(u32, __builtin_amdgcn_exp2f(St[kt][qt][r]));
          t[kt * 4 + r] = (bf16)__builtin_bit_cast(float, pe & (u32)mb);
        }
      pf8[qt] = t;
    }
    __builtin_amdgcn_s_setprio(1);
    // rowsum via ones-column on the MFMA pipe (K=32)
    #pragma unroll
    for (int qt = 0; qt < 2; ++qt)
      Ol[qt] = __builtin_amdgcn_mfma_f32_16x16x32_bf16(
          pf8[qt], ones8, Ol[qt], 0, 0, 0);
    // O += P V  (one b128 V read per dt, shared across qt)
    #pragma unroll
    for (int dt = 0; dt < 4; ++dt) {
      int d = dt * 16 + lo;
      int c = (kh * 4 + quad) ^ SWZ(d);
      bf16x8_t vf = *(const bf16x8_t*)(bV + d * 128 + c * 16);
      #pragma unroll
      for (int qt = 0; qt < 2; ++qt)
        O[qt][dt] = __builtin_amdgcn_mfma_f32_16x16x32_bf16(
            pf8[qt], vf, O[qt][dt], 0, 0, 0);
    }
    __builtin_amdgcn_s_setprio(0);
  }

  // ---- epilogue: 4-way kh combine (barrier-sequenced) ----
  __syncthreads();                      // main-loop buffers now dead
  float* smO = (float*)smem;            // 64x64 f32 = 16KB (over K0+V0)
  bf16* smOut = (bf16*)(smem + 16384);  // 8KB bf16 out tile (over K1)
  if (lo == 0) {
    #pragma unroll
    for (int qt = 0; qt < 2; ++qt)
      #pragma unroll
      for (int r = 0; r < 4; ++r)
        smL[khh * 64 + qh * 32 + qt * 16 + quad * 4 + r] = Ol[qt][r];
  }
  if (khh == 3) {
    #pragma unroll
    for (int qt = 0; qt < 2; ++qt)
      #pragma unroll
      for (int dt = 0; dt < 4; ++dt)
        #pragma unroll
        for (int r = 0; r < 4; ++r)
          smO[(qh * 32 + qt * 16 + quad * 4 + r) * 64 + dt * 16 + lo] = O[qt][dt][r];
  }
  __syncthreads();
  if (khh == 2) {
    #pragma unroll
    for (int qt = 0; qt < 2; ++qt)
      #pragma unroll
      for (int dt = 0; dt < 4; ++dt)
        #pragma unroll
        for (int r = 0; r < 4; ++r)
          smO[(qh * 32 + qt * 16 + quad * 4 + r) * 64 + dt * 16 + lo] += O[qt][dt][r];
  }
  __syncthreads();
  if (khh == 1) {
    #pragma unroll
    for (int qt = 0; qt < 2; ++qt)
      #pragma unroll
      for (int dt = 0; dt < 4; ++dt)
        #pragma unroll
        for (int r = 0; r < 4; ++r)
          smO[(qh * 32 + qt * 16 + quad * 4 + r) * 64 + dt * 16 + lo] += O[qt][dt][r];
  }
  __syncthreads();
  if (khh == 0) {
    #pragma unroll
    for (int qt = 0; qt < 2; ++qt) {
      #pragma unroll
      for (int r = 0; r < 4; ++r) {
        int row = qh * 32 + qt * 16 + quad * 4 + r;
        float s = smL[row] + smL[64 + row] + smL[128 + row] + smL[192 + row];
        float inv = 1.0f / s;
        #pragma unroll
        for (int dt = 0; dt < 4; ++dt) {
          float o = (O[qt][dt][r] + smO[row * 64 + dt * 16 + lo]) * inv;
          smOut[row * 64 + dt * 16 + lo] = (bf16)o;
        }
      }
    }
  }
  __syncthreads();
  // coalesced copy-out: 8192B contiguous block, 16B per lane (512 threads)
  {
    bf16* Og = Obuf + ((size_t)bh * T_ + qbase) * DH_;
    *(bf16x8_t*)(Og + tid * 8) = *(const bf16x8_t*)(smOut + tid * 8);
  }
}

// ------------------------------------------------------ output proj --------
// 64x64 tiles, operand-swapped; LDS-transpose epilogue -> coalesced stores.
__global__ __launch_bounds__(256) void proj_kernel(
    const bf16* __restrict__ Obuf, const bf16* __restrict__ WoT,
    const float* __restrict__ bo, float* __restrict__ out)
{
  __shared__ char smem[16384];
  char* smA = smem;
  char* smW = smem + 8192;
  int tid = threadIdx.x;
  int lane = tid & 63, wave = tid >> 6;
  int lo = lane & 15, quad = lane >> 4;
  int wr = wave >> 1, wc = wave & 1;
  int bm = blockIdx.x * 64;
  int bn = blockIdx.y * 64;
  int b_ = bm >> 12, trow = bm & 4095;
  f32x4 acc[2][2] = {};
  for (int kc = 0; kc < 8; ++kc) {
    __syncthreads();
    const bf16* Ag = Obuf + ((size_t)(b_ * H_ + kc) * T_ + trow) * DH_;
    for (int s = tid; s < 512; s += 256) {
      int row = s >> 3, slot = s & 7;
      int cg = slot ^ (row & 7) ^ ((row >> 3) & 1);
      async16(smA + s * 16, Ag + row * 64 + cg * 8);
      async16(smW + s * 16, WoT + (size_t)(bn + row) * 512 + kc * 64 + cg * 8);
    }
    __syncthreads();
    #pragma unroll
    for (int ks = 0; ks < 2; ++ks) {
      bf16x8_t a[2], b[2];
      #pragma unroll
      for (int mt = 0; mt < 2; ++mt) {
        int row = wr * 32 + mt * 16 + lo;
        int ch = (ks * 4 + quad) ^ (row & 7) ^ ((row >> 3) & 1);
        a[mt] = *(const bf16x8_t*)(smA + row * 128 + ch * 16);
      }
      #pragma unroll
      for (int nt = 0; nt < 2; ++nt) {
        int row = wc * 32 + nt * 16 + lo;
        int ch = (ks * 4 + quad) ^ (row & 7) ^ ((row >> 3) & 1);
        b[nt] = *(const bf16x8_t*)(smW + row * 128 + ch * 16);
      }
      #pragma unroll
      for (int mt = 0; mt < 2; ++mt)
        #pragma unroll
        for (int nt = 0; nt < 2; ++nt)
          acc[mt][nt] = __builtin_amdgcn_mfma_f32_16x16x32_bf16(
              b[nt], a[mt], acc[mt][nt], 0, 0, 0);   // D: m=out-col, n=t
    }
  }
  // ---- epilogue: acc -> swizzled LDS f32 tile -> coalesced copy-out ----
  __syncthreads();
  char* smT = smem;                     // 64x64 f32 = 16384 B, 16B chunks swz
  #pragma unroll
  for (int mt = 0; mt < 2; ++mt) {
    int tl = wr * 32 + mt * 16 + lo;
    #pragma unroll
    for (int nt = 0; nt < 2; ++nt) {
      int c0 = wc * 32 + nt * 16 + quad * 4;
      f32x4 v;
      #pragma unroll
      for (int r = 0; r < 4; ++r) v[r] = acc[mt][nt][r] + bo[bn + c0 + r];
      int chunk = (c0 >> 2) ^ (tl & 15);
      *(f32x4*)(smT + tl * 256 + chunk * 16) = v;
    }
  }
  __syncthreads();
  #pragma unroll
  for (int it = 0; it < 4; ++it) {
    int i = tid + it * 256;
    int tl = i >> 4, c = i & 15;
    f32x4 v = *(const f32x4*)(smT + tl * 256 + ((c ^ (tl & 15)) * 16));
    *(f32x4*)(out + (size_t)(bm + tl) * 512 + bn + c * 4) = v;
  }
}

// --------------------------------------------------------------- launch ----
extern "C" void kernel_launch(void* const* d_in, const int* in_sizes, int n_in,
                              void* d_out, int out_size, void* d_ws, size_t ws_size,
                              hipStream_t stream) {
  const float* x  = (const float*)d_in[0];
  const float* Wq = (const float*)d_in[1];
  const float* bq = (const float*)d_in[2];
  const float* Wk = (const float*)d_in[3];
  const float* bk = (const float*)d_in[4];
  const float* Wv = (const float*)d_in[5];
  const float* bv = (const float*)d_in[6];
  const float* Wo = (const float*)d_in[7];
  const float* bo = (const float*)d_in[8];
  const void* maskp = d_in[9];
  float* out = (float*)d_out;

  char* w = (char*)d_ws;
  bf16* xb    = (bf16*)(w);              //  8,388,608 B
  bf16* WTall = (bf16*)(w + 8388608);    //  1,572,864 B
  bf16* WoT   = (bf16*)(w + 9961472);    //    524,288 B
  bf16* Qb    = (bf16*)(w + 10485760);   //  8,388,608 B
  bf16* Kb    = (bf16*)(w + 18874368);   //  8,388,608 B
  bf16* Vtb   = (bf16*)(w + 27262976);   //  8,388,608 B  (B,H,64,T)
  bf16* Obuf  = (bf16*)(w + 35651584);   //  8,388,608 B
  u32*  bmask = (u32*)(w + 44040192);    //  2,097,152 B

  prep_kernel<<<10240, 256, 0, stream>>>(x, Wq, Wk, Wv, Wo, maskp,
                                         xb, WTall, WoT, bmask);
  qkv_kernel<<<dim3(64, 12), 256, 0, stream>>>(xb, WTall, bq, bk, bv,
                                               Qb, Kb, Vtb);
  attn_kernel<<<1024, 512, 0, stream>>>(Qb, Kb, Vtb, bmask, Obuf);
  proj_kernel<<<dim3(128, 8), 256, 0, stream>>>(Obuf, WoT, bo, out);
}

// Round 9
// 267.064 us; speedup vs baseline: 3.0216x; 3.0216x over previous
//
#include <hip/hip_runtime.h>
#include <stdint.h>

#define B_ 2
#define T_ 4096
#define D_ 512
#define H_ 8
#define DH_ 64

typedef __bf16 bf16;
typedef __bf16 bf16x4_t __attribute__((ext_vector_type(4)));
typedef __bf16 bf16x8_t __attribute__((ext_vector_type(8)));
typedef float f32x4 __attribute__((ext_vector_type(4)));
typedef short short4_t __attribute__((ext_vector_type(4)));
typedef uint32_t u32;

static constexpr float QSCALE = 0.18033688011112042f;   // log2(e)/8 (folded into Wq,bq)

__device__ __forceinline__ void async16(void* lds, const void* g) {
  __builtin_amdgcn_global_load_lds(
      (const __attribute__((address_space(1))) void*)g,
      (__attribute__((address_space(3))) void*)lds, 16, 0, 0);
}

// ---------------------------------------------------------------- prep ----
__global__ __launch_bounds__(256) void prep_kernel(
    const float* __restrict__ x,
    const float* __restrict__ Wq, const float* __restrict__ Wk,
    const float* __restrict__ Wv, const float* __restrict__ Wo,
    const void* __restrict__ maskp,
    bf16* __restrict__ xb, bf16* __restrict__ WTall, bf16* __restrict__ WoT,
    u32* __restrict__ bmask)
{
  int bid = blockIdx.x;
  int tid = threadIdx.x;
  if (bid < 4096) {
    int idx = bid * 256 + tid;
    const float4* xf = (const float4*)x;
    float4 v = xf[idx];
    bf16x4_t o;
    o[0] = (bf16)v.x; o[1] = (bf16)v.y; o[2] = (bf16)v.z; o[3] = (bf16)v.w;
    ((bf16x4_t*)xb)[idx] = o;
  } else if (bid < 8192) {
    int gid = (bid - 4096) * 256 + tid;
    int sel = gid >> 18;
    int idx = gid & 262143;
    int n = idx >> 9, k = idx & 511;
    if (sel < 3) {
      const float* W = (sel == 0) ? Wq : (sel == 1) ? Wk : Wv;
      float v = W[k * 512 + n];
      if (sel == 0) v *= QSCALE;
      WTall[gid] = (bf16)v;
    } else {
      WoT[idx] = (bf16)Wo[k * 512 + n];
    }
  } else {
    int wid = (bid - 8192) * 256 + tid;   // 524,288 words
    const uint8_t* m8 = (const uint8_t*)maskp;
    bool u8mode = (__ballot(m8[4 * (tid & 63) + 1] != 0) != 0ull);
    int row = wid >> 7, wcol = wid & 127;
    size_t off = (size_t)row * 4096 + (size_t)wcol * 32;
    u32 w = 0;
    if (u8mode) {
      const uint4* p = (const uint4*)(m8 + off);
      uint4 a = p[0], b = p[1];
      u32 ws[8] = {a.x, a.y, a.z, a.w, b.x, b.y, b.z, b.w};
      #pragma unroll
      for (int j = 0; j < 32; ++j)
        if ((ws[j >> 2] >> ((j & 3) * 8)) & 0xffu) w |= (1u << j);
    } else {
      const uint4* p = (const uint4*)((const u32*)maskp + off);
      #pragma unroll
      for (int q = 0; q < 8; ++q) {
        uint4 a = p[q];
        if (a.x) w |= 1u << (q * 4 + 0);
        if (a.y) w |= 1u << (q * 4 + 1);
        if (a.z) w |= 1u << (q * 4 + 2);
        if (a.w) w |= 1u << (q * 4 + 3);
      }
    }
    bmask[((size_t)(row >> 6) * 64 + (wcol >> 1)) * 128 + (row & 63) * 2 + (wcol & 1)] = w;
  }
}

// ---------------------------------------------------------- QKV GEMM -------
// 128x128 tiles: 4 waves, each owns a 64x64 sub-tile. BK=64, 2-barrier.
// LDS-transpose epilogue -> fully coalesced 16B output stores.
__global__ __launch_bounds__(256) void qkv_kernel(
    const bf16* __restrict__ xb, const bf16* __restrict__ WTall,
    const float* __restrict__ bq, const float* __restrict__ bk,
    const float* __restrict__ bv,
    bf16* __restrict__ Qb, bf16* __restrict__ Kb, bf16* __restrict__ Vtb)
{
  __shared__ char smem[32768];
  char* smX = smem;                 // 128 rows x 128B (swizzled)
  char* smW = smem + 16384;         // 128 rows x 128B
  int tid = threadIdx.x;
  int lane = tid & 63, wave = tid >> 6;
  int lo = lane & 15, quad = lane >> 4;
  int wr = wave >> 1, wc = wave & 1;
  int bm = blockIdx.x * 128;
  int bn = blockIdx.y * 128;
  int sel = bn >> 9;   // 0=Q 1=K 2=V
  f32x4 acc[4][4] = {};
  for (int kc = 0; kc < 8; ++kc) {
    __syncthreads();
    #pragma unroll
    for (int i = 0; i < 4; ++i) {
      int s = tid + i * 256;
      int row = s >> 3, slot = s & 7;
      int cg = slot ^ (row & 7) ^ ((row >> 3) & 1);
      async16(smX + s * 16, xb + (size_t)(bm + row) * 512 + kc * 64 + cg * 8);
      async16(smW + s * 16, WTall + (size_t)(bn + row) * 512 + kc * 64 + cg * 8);
    }
    __syncthreads();
    #pragma unroll
    for (int ks = 0; ks < 2; ++ks) {
      bf16x8_t a[4], b[4];
      #pragma unroll
      for (int mt = 0; mt < 4; ++mt) {
        int row = wr * 64 + mt * 16 + lo;
        int ch = (ks * 4 + quad) ^ (row & 7) ^ ((row >> 3) & 1);
        a[mt] = *(const bf16x8_t*)(smX + row * 128 + ch * 16);
      }
      #pragma unroll
      for (int nt = 0; nt < 4; ++nt) {
        int row = wc * 64 + nt * 16 + lo;
        int ch = (ks * 4 + quad) ^ (row & 7) ^ ((row >> 3) & 1);
        b[nt] = *(const bf16x8_t*)(smW + row * 128 + ch * 16);
      }
      if (sel < 2) {
        #pragma unroll
        for (int mt = 0; mt < 4; ++mt)
          #pragma unroll
          for (int nt = 0; nt < 4; ++nt)
            acc[mt][nt] = __builtin_amdgcn_mfma_f32_16x16x32_bf16(
                b[nt], a[mt], acc[mt][nt], 0, 0, 0);   // D: m=W-row, n=t
      } else {
        #pragma unroll
        for (int mt = 0; mt < 4; ++mt)
          #pragma unroll
          for (int nt = 0; nt < 4; ++nt)
            acc[mt][nt] = __builtin_amdgcn_mfma_f32_16x16x32_bf16(
                a[mt], b[nt], acc[mt][nt], 0, 0, 0);   // D: m=t, n=W-row
      }
    }
  }
  int b_ = bm >> 12;
  // ---- epilogue: acc -> swizzled LDS tile -> coalesced 16B copy-out ----
  __syncthreads();                      // all waves done reading smX/smW
  char* smT = smem;                     // 128x128 bf16 = 32768 B, chunk-swizzled
  if (sel < 2) {
    const float* bias = (sel == 0) ? bq : bk;
    bf16* base = (sel == 0) ? Qb : Kb;
    #pragma unroll
    for (int mt = 0; mt < 4; ++mt) {
      int tl = wr * 64 + mt * 16 + lo;
      #pragma unroll
      for (int nt = 0; nt < 4; ++nt) {
        int c0 = wc * 64 + nt * 16 + quad * 4;
        bf16x4_t v;
        #pragma unroll
        for (int r = 0; r < 4; ++r) {
          float bs = bias[(bn & 511) + c0 + r];
          if (sel == 0) bs *= QSCALE;
          v[r] = (bf16)(acc[mt][nt][r] + bs);
        }
        int chunk = (c0 >> 3) ^ (tl & 15);
        int half = (c0 >> 2) & 1;
        *(bf16x4_t*)(smT + tl * 256 + chunk * 16 + half * 8) = v;
      }
    }
    __syncthreads();
    #pragma unroll
    for (int it = 0; it < 8; ++it) {
      int i = tid + it * 256;
      int tl = i >> 4, c = i & 15;
      bf16x8_t v = *(const bf16x8_t*)(smT + tl * 256 + ((c ^ (tl & 15)) * 16));
      int colg = (bn & 511) + c * 8;
      int h = colg >> 6, dh0 = colg & 63;
      int t = (bm & 4095) + tl;
      *(bf16x8_t*)(base + (size_t)(b_ * H_ + h) * T_ * DH_ +
                   (size_t)t * 64 + dh0) = v;
    }
  } else {
    #pragma unroll
    for (int nt = 0; nt < 4; ++nt) {
      int dhl = wc * 64 + nt * 16 + lo;
      float bs = bv[(bn & 511) + dhl];
      #pragma unroll
      for (int mt = 0; mt < 4; ++mt) {
        int t0 = wr * 64 + mt * 16 + quad * 4;
        bf16x4_t v;
        #pragma unroll
        for (int r = 0; r < 4; ++r) v[r] = (bf16)(acc[mt][nt][r] + bs);
        int chunk = (t0 >> 3) ^ (dhl & 15);
        int half = (t0 >> 2) & 1;
        *(bf16x4_t*)(smT + dhl * 256 + chunk * 16 + half * 8) = v;
      }
    }
    __syncthreads();
    #pragma unroll
    for (int it = 0; it < 8; ++it) {
      int i = tid + it * 256;
      int dhl = i >> 4, c = i & 15;
      bf16x8_t v = *(const bf16x8_t*)(smT + dhl * 256 + ((c ^ (dhl & 15)) * 16));
      int colg = (bn & 511) + dhl;
      int h = colg >> 6, dh = colg & 63;
      int t = (bm & 4095) + c * 8;
      *(bf16x8_t*)(Vtb + ((size_t)(b_ * H_ + h) * DH_ + dh) * T_ + t) = v;
    }
  }
}

// ------------------------------------------------------ flash attention ----
// QBLK=128 with 8 waves (qh in 0..3, kh in 0..1), launch_bounds(512, 4)
// -> VGPR cap 128. Per-wave inner code identical to the proven R4 form
// (32q x 32k per 64-key chunk). Gains vs R4: staging instrs/thread halve,
// barrier drains per q-row halve (64 chunks serve 128 rows).
// ROUND-9 FIX: copy-out is 2 iterations (16384B smOut / 8192B per iter);
// round-8's 4 iterations overran smOut AND the 128-row Obuf tile,
// clobbering other blocks' output with garbage -> NaN.
#define SWZ(r) (((r) & 3) | ((((r) >> 3) & 1) << 2))

__global__ __launch_bounds__(512, 4) void attn_kernel(
    const bf16* __restrict__ Qb, const bf16* __restrict__ Kb,
    const bf16* __restrict__ Vtb, const u32* __restrict__ bm2,
    bf16* __restrict__ Obuf)
{
  __shared__ char smem[50176];
  // main: [0,8192) K | [8192,16384) V | [16384,17408) mask (256 words)
  // epi:  smO f32 [0,32768) | smLa [32768,33280) | smLb [33280,33792)
  //       smOut bf16 [33792,50176)
  char* smK = smem;
  char* smV = smem + 8192;
  u32* smM = (u32*)(smem + 16384);
  float* smLa = (float*)(smem + 32768);  // 128 f32 rowsum partials kh=0
  float* smLb = (float*)(smem + 33280);  // 128 f32 rowsum partials kh=1
  int tid = threadIdx.x;
  int lane = tid & 63, wave = tid >> 6;   // 0..7
  int lo = lane & 15, quad = lane >> 4;
  int qh = wave >> 1;                     // 0..3: 32-row q strip
  int kh = wave & 1;                      // 0..1: 32-key strip
  int blk = blockIdx.x;
  int bh = blk & 15;                      // XCD-aware: bh pinned per XCD
  int qt128 = blk >> 4;                   // 0..31
  int qbase = qt128 * 128;

  const bf16* Kg = Kb + (size_t)bh * T_ * DH_;
  const bf16* Vg = Vtb + (size_t)bh * DH_ * T_;
  const u32* mg = bm2 + ((size_t)qt128 * 2) * 8192;   // two 64-row groups

  // preload Q fragments (loop-invariant); B operand of mfma(K,Q)
  const bf16* Qg = Qb + ((size_t)bh * T_ + qbase + qh * 32) * DH_;
  bf16x8_t qf[2][2];
  #pragma unroll
  for (int qt = 0; qt < 2; ++qt)
    #pragma unroll
    for (int ks = 0; ks < 2; ++ks)
      qf[qt][ks] = *(const bf16x8_t*)(Qg + (qt * 16 + lo) * 64 + ks * 32 + quad * 8);

  // ones-column B-frag for K=32 rowsum MFMA (col n=0 -> lanes lo==0)
  bf16 onev = (lo == 0) ? (bf16)1.0f : (bf16)0.0f;
  bf16x8_t ones8 = {onev, onev, onev, onev, onev, onev, onev, onev};

  f32x4 O[2][4] = {};
  f32x4 Ol[2] = {};

  for (int kc = 0; kc < 64; ++kc) {
    __syncthreads();                    // prior compute done: safe to restage
    {
      int row = tid >> 3, slot = tid & 7;   // 512 threads: 64 rows x 8 slots
      int cg = slot ^ SWZ(row);
      async16(smK + tid * 16, Kg + (size_t)(kc * 64 + row) * 64 + cg * 8);
      async16(smV + tid * 16, Vg + (size_t)row * T_ + kc * 64 + cg * 8);
    }
    if (tid < 64) {
      int g = tid >> 5, wv = tid & 31;      // 2 groups x 512B
      async16((char*)smM + tid * 16,
              mg + ((size_t)(g * 64 + kc)) * 128 + wv * 4);
    }
    __syncthreads();                    // staging visible
    // S^T = K Q^T; permuted K-row feed:
    // krow = kh*32 + (lo>>2)*8 + kt*4 + (lo&3)
    //  -> St[kt][qt][r] holds k(within chunk) = kh*32 + quad*8 + kt*4 + r
    f32x4 St[2][2] = {};
    __builtin_amdgcn_s_setprio(1);
    #pragma unroll
    for (int ks = 0; ks < 2; ++ks)
      #pragma unroll
      for (int kt = 0; kt < 2; ++kt) {
        int krow = kh * 32 + ((lo >> 2) << 3) + kt * 4 + (lo & 3);
        int ch = (ks * 4 + quad) ^ SWZ(krow);
        bf16x8_t kf = *(const bf16x8_t*)(smK + krow * 128 + ch * 16);
        #pragma unroll
        for (int qt = 0; qt < 2; ++qt)
          St[kt][qt] = __builtin_amdgcn_mfma_f32_16x16x32_bf16(
              kf, qf[qt][ks], St[kt][qt], 0, 0, 0);
      }
    __builtin_amdgcn_s_setprio(0);
    // mask (sext bitfield + AND) + exp2 + pack to K=32 PV A-frags
    bf16x8_t pf8[2];   // [qt]: elem j=kt*4+r -> k = kh*32 + quad*8 + j
    #pragma unroll
    for (int qt = 0; qt < 2; ++qt) {
      int qrow = qh * 32 + qt * 16 + lo;          // 0..127
      u32 w = smM[(qrow >> 6) * 128 + (qrow & 63) * 2 + kh];
      bf16x8_t t;
      #pragma unroll
      for (int kt = 0; kt < 2; ++kt)
        #pragma unroll
        for (int r = 0; r < 4; ++r) {
          int bit = quad * 8 + kt * 4 + r;
          int mb = ((int)(w << (31 - bit))) >> 31;
          u32 pe = __builtin_bit_cast(u32, __builtin_amdgcn_exp2f(St[kt][qt][r]));
          t[kt * 4 + r] = (bf16)__builtin_bit_cast(float, pe & (u32)mb);
        }
      pf8[qt] = t;
    }
    __builtin_amdgcn_s_setprio(1);
    // rowsum via ones-column on the MFMA pipe (K=32)
    #pragma unroll
    for (int qt = 0; qt < 2; ++qt)
      Ol[qt] = __builtin_amdgcn_mfma_f32_16x16x32_bf16(
          pf8[qt], ones8, Ol[qt], 0, 0, 0);
    // O += P V  (one b128 V read per dt, shared across qt)
    #pragma unroll
    for (int dt = 0; dt < 4; ++dt) {
      int d = dt * 16 + lo;
      int c = (kh * 4 + quad) ^ SWZ(d);
      bf16x8_t vf = *(const bf16x8_t*)(smV + d * 128 + c * 16);
      #pragma unroll
      for (int qt = 0; qt < 2; ++qt)
        O[qt][dt] = __builtin_amdgcn_mfma_f32_16x16x32_bf16(
            pf8[qt], vf, O[qt][dt], 0, 0, 0);
    }
    __builtin_amdgcn_s_setprio(0);
  }

  // ---- epilogue: rowsums in lanes lo==0 of Ol; 2-way kh combine ----
  __syncthreads();                      // main-loop buffers now dead
  float* smO = (float*)smem;            // 128 x 64 f32 = 32KB (over K,V,M)
  bf16* smOut = (bf16*)(smem + 33792);  // 16KB final bf16 out tile
  if (lo == 0) {
    float* dst = (kh == 0) ? smLa : smLb;
    #pragma unroll
    for (int qt = 0; qt < 2; ++qt)
      #pragma unroll
      for (int r = 0; r < 4; ++r)
        dst[qh * 32 + qt * 16 + quad * 4 + r] = Ol[qt][r];
  }
  if (kh == 1) {
    #pragma unroll
    for (int qt = 0; qt < 2; ++qt)
      #pragma unroll
      for (int dt = 0; dt < 4; ++dt)
        #pragma unroll
        for (int r = 0; r < 4; ++r)
          smO[(qh * 32 + qt * 16 + quad * 4 + r) * 64 + dt * 16 + lo] = O[qt][dt][r];
  }
  __syncthreads();
  if (kh == 0) {
    #pragma unroll
    for (int qt = 0; qt < 2; ++qt) {
      #pragma unroll
      for (int r = 0; r < 4; ++r) {
        int row = qh * 32 + qt * 16 + quad * 4 + r;
        float inv = 1.0f / (smLa[row] + smLb[row]);
        #pragma unroll
        for (int dt = 0; dt < 4; ++dt) {
          float o = (O[qt][dt][r] + smO[row * 64 + dt * 16 + lo]) * inv;
          smOut[row * 64 + dt * 16 + lo] = (bf16)o;
        }
      }
    }
  }
  __syncthreads();
  // coalesced copy-out: 16384B contiguous = 2 iters x 512 threads x 16B
  {
    bf16* Og = Obuf + ((size_t)bh * T_ + qbase) * DH_;
    #pragma unroll
    for (int it = 0; it < 2; ++it) {
      int i = tid + it * 512;
      *(bf16x8_t*)(Og + i * 8) = *(const bf16x8_t*)(smOut + i * 8);
    }
  }
}

// ------------------------------------------------------ output proj --------
// 64x64 tiles, operand-swapped; LDS-transpose epilogue -> coalesced stores.
__global__ __launch_bounds__(256) void proj_kernel(
    const bf16* __restrict__ Obuf, const bf16* __restrict__ WoT,
    const float* __restrict__ bo, float* __restrict__ out)
{
  __shared__ char smem[16384];
  char* smA = smem;
  char* smW = smem + 8192;
  int tid = threadIdx.x;
  int lane = tid & 63, wave = tid >> 6;
  int lo = lane & 15, quad = lane >> 4;
  int wr = wave >> 1, wc = wave & 1;
  int bm = blockIdx.x * 64;
  int bn = blockIdx.y * 64;
  int b_ = bm >> 12, trow = bm & 4095;
  f32x4 acc[2][2] = {};
  for (int kc = 0; kc < 8; ++kc) {
    __syncthreads();
    const bf16* Ag = Obuf + ((size_t)(b_ * H_ + kc) * T_ + trow) * DH_;
    for (int s = tid; s < 512; s += 256) {
      int row = s >> 3, slot = s & 7;
      int cg = slot ^ (row & 7) ^ ((row >> 3) & 1);
      async16(smA + s * 16, Ag + row * 64 + cg * 8);
      async16(smW + s * 16, WoT + (size_t)(bn + row) * 512 + kc * 64 + cg * 8);
    }
    __syncthreads();
    #pragma unroll
    for (int ks = 0; ks < 2; ++ks) {
      bf16x8_t a[2], b[2];
      #pragma unroll
      for (int mt = 0; mt < 2; ++mt) {
        int row = wr * 32 + mt * 16 + lo;
        int ch = (ks * 4 + quad) ^ (row & 7) ^ ((row >> 3) & 1);
        a[mt] = *(const bf16x8_t*)(smA + row * 128 + ch * 16);
      }
      #pragma unroll
      for (int nt = 0; nt < 2; ++nt) {
        int row = wc * 32 + nt * 16 + lo;
        int ch = (ks * 4 + quad) ^ (row & 7) ^ ((row >> 3) & 1);
        b[nt] = *(const bf16x8_t*)(smW + row * 128 + ch * 16);
      }
      #pragma unroll
      for (int mt = 0; mt < 2; ++mt)
        #pragma unroll
        for (int nt = 0; nt < 2; ++nt)
          acc[mt][nt] = __builtin_amdgcn_mfma_f32_16x16x32_bf16(
              b[nt], a[mt], acc[mt][nt], 0, 0, 0);   // D: m=out-col, n=t
    }
  }
  // ---- epilogue: acc -> swizzled LDS f32 tile -> coalesced copy-out ----
  __syncthreads();
  char* smT = smem;                     // 64x64 f32 = 16384 B, 16B chunks swz
  #pragma unroll
  for (int mt = 0; mt < 2; ++mt) {
    int tl = wr * 32 + mt * 16 + lo;
    #pragma unroll
    for (int nt = 0; nt < 2; ++nt) {
      int c0 = wc * 32 + nt * 16 + quad * 4;
      f32x4 v;
      #pragma unroll
      for (int r = 0; r < 4; ++r) v[r] = acc[mt][nt][r] + bo[bn + c0 + r];
      int chunk = (c0 >> 2) ^ (tl & 15);
      *(f32x4*)(smT + tl * 256 + chunk * 16) = v;
    }
  }
  __syncthreads();
  #pragma unroll
  for (int it = 0; it < 4; ++it) {
    int i = tid + it * 256;
    int tl = i >> 4, c = i & 15;
    f32x4 v = *(const f32x4*)(smT + tl * 256 + ((c ^ (tl & 15)) * 16));
    *(f32x4*)(out + (size_t)(bm + tl) * 512 + bn + c * 4) = v;
  }
}

// --------------------------------------------------------------- launch ----
extern "C" void kernel_launch(void* const* d_in, const int* in_sizes, int n_in,
                              void* d_out, int out_size, void* d_ws, size_t ws_size,
                              hipStream_t stream) {
  const float* x  = (const float*)d_in[0];
  const float* Wq = (const float*)d_in[1];
  const float* bq = (const float*)d_in[2];
  const float* Wk = (const float*)d_in[3];
  const float* bk = (const float*)d_in[4];
  const float* Wv = (const float*)d_in[5];
  const float* bv = (const float*)d_in[6];
  const float* Wo = (const float*)d_in[7];
  const float* bo = (const float*)d_in[8];
  const void* maskp = d_in[9];
  float* out = (float*)d_out;

  char* w = (char*)d_ws;
  bf16* xb    = (bf16*)(w);              //  8,388,608 B
  bf16* WTall = (bf16*)(w + 8388608);    //  1,572,864 B
  bf16* WoT   = (bf16*)(w + 9961472);    //    524,288 B
  bf16* Qb    = (bf16*)(w + 10485760);   //  8,388,608 B
  bf16* Kb    = (bf16*)(w + 18874368);   //  8,388,608 B
  bf16* Vtb   = (bf16*)(w + 27262976);   //  8,388,608 B  (B,H,64,T)
  bf16* Obuf  = (bf16*)(w + 35651584);   //  8,388,608 B
  u32*  bmask = (u32*)(w + 44040192);    //  2,097,152 B

  prep_kernel<<<10240, 256, 0, stream>>>(x, Wq, Wk, Wv, Wo, maskp,
                                         xb, WTall, WoT, bmask);
  qkv_kernel<<<dim3(64, 12), 256, 0, stream>>>(xb, WTall, bq, bk, bv,
                                               Qb, Kb, Vtb);
  attn_kernel<<<512, 512, 0, stream>>>(Qb, Kb, Vtb, bmask, Obuf);
  proj_kernel<<<dim3(128, 8), 256, 0, stream>>>(Obuf, WoT, bo, out);
}